// Round 3
// baseline (5920.965 us; speedup 1.0000x reference)
//
#include <hip/hip_runtime.h>
#include <hip/hip_bf16.h>

// EA-LSTM persistent kernel for MI355X (gfx950), round 3.
// B=128, T=2048, DYN=8, STAT=24, H=256, OUT=1.
// 32 WGs x 512 threads (8 waves); WG owns 4 batch rows (M=16 MFMA tile, rows
// 4..15 are finite pad). Wave w owns channels [w*32, w*32+32) of every gate.
// After the MFMA phase, pre-activations are redistributed INTRA-WAVE through
// per-wave LDS scratch so every lane owns 2 (row,ch) gate-sets -> activation
// instruction count per SIMD drops 4x vs round 2.
// Weights: f,g all K-steps + o K-step 7 + x-proj fragments in registers;
// o K-steps 0..6 in LDS. h exchanged via double-buffered A tile, 1 barrier/step.

#define T_LEN 2048
#define HD 256

typedef __attribute__((ext_vector_type(8))) short bf16x8;
typedef __attribute__((ext_vector_type(4))) float f32x4;

#define LOG2E 1.4426950408889634f

__device__ __forceinline__ short f2bf(float f) {
  unsigned u = __float_as_uint(f);
  unsigned r = (u + 0x7fffu + ((u >> 16) & 1u)) >> 16;
  return (short)r;
}

__device__ __forceinline__ bf16x8 loadw8(const float* p) {
  bf16x8 r;
#pragma unroll
  for (int i = 0; i < 8; ++i) r[i] = f2bf(p[i]);
  return r;
}

__device__ __forceinline__ float sigm(float x) {
  float e = __builtin_amdgcn_exp2f(-LOG2E * x);
  return __builtin_amdgcn_rcpf(1.0f + e);
}

__device__ __forceinline__ float tanh_(float x) {
  float xc = fminf(fmaxf(x, -15.0f), 15.0f);
  float e = __builtin_amdgcn_exp2f(2.0f * LOG2E * xc);
  return (e - 1.0f) * __builtin_amdgcn_rcpf(e + 1.0f);
}

// A tile: 16 rows x 296 cols bf16 (0..255 = h, 256..287 = x_t, 288+ pad).
// Row stride 296 shorts = 592 B; dword stride 148 === 20 mod 32 -> 2-way banks (free).
#define ASTR 296
#define ABUF (16 * ASTR)

__global__ __launch_bounds__(512, 2) void ealstm_kernel(
    const float* __restrict__ x, const float* __restrict__ c0, const float* __restrict__ h0,
    const float* __restrict__ Wi, const float* __restrict__ bi,
    const float* __restrict__ Wfx, const float* __restrict__ bfx,
    const float* __restrict__ Wfh, const float* __restrict__ bfh,
    const float* __restrict__ Wgx, const float* __restrict__ bgx,
    const float* __restrict__ Wgh, const float* __restrict__ bgh,
    const float* __restrict__ Wox, const float* __restrict__ box_,
    const float* __restrict__ Woh, const float* __restrict__ boh,
    const float* __restrict__ Wout, const float* __restrict__ bout,
    float* __restrict__ out)
{
  __shared__ __attribute__((aligned(16))) short A_sh[2 * ABUF];        // 18944 B
  __shared__ __attribute__((aligned(16))) short Bo_sh[8 * 14 * 512];   // 114688 B
  __shared__ __attribute__((aligned(16))) float R_sh[8 * 8 * 16 * 4];  // 16384 B
  __shared__ float out_part[2][4][8];                                  // 256 B

  const int tid = threadIdx.x;
  const int w   = tid >> 6;   // wave 0..7
  const int l   = tid & 63;
  const int lr  = l & 15;     // MFMA col / lambda
  const int lg  = l >> 4;     // MFMA row-group / rho (row index after redistr.)
  const int n0  = w * 32;
  const int wg  = blockIdx.x; // 4-row batch block

  // ---- register-resident weights ----
  bf16x8 Bf[8][2], Bg[8][2], Bo7[2], Bx[4][2];
#pragma unroll
  for (int ks = 0; ks < 8; ++ks) {
#pragma unroll
    for (int nt = 0; nt < 2; ++nt) {
      const int n = n0 + nt * 16 + lr;
      const int k = ks * 32 + lg * 8;
      Bf[ks][nt] = loadw8(Wfh + n * HD + k);
      Bg[ks][nt] = loadw8(Wgh + n * HD + k);
    }
  }
  {
    bf16x8 z = (bf16x8)(short)0;
    const float* WxArr[3] = {Wfx, Wgx, Wox};
#pragma unroll
    for (int nt = 0; nt < 2; ++nt) {
      const int n = n0 + nt * 16 + lr;
      Bo7[nt] = loadw8(Woh + n * HD + 7 * 32 + lg * 8);
#pragma unroll
      for (int g = 0; g < 3; ++g) {
        Bx[g][nt] = (lg == 0) ? loadw8(WxArr[g] + n * 8) : z;
      }
      Bx[3][nt] = (lg >= 1) ? loadw8(Wi + n * 24 + (lg - 1) * 8) : z;
    }
  }

  // ---- LDS-resident: o-gate K-steps 0..6 ----
  short* bo = Bo_sh + w * (14 * 512);
#pragma unroll
  for (int ks = 0; ks < 7; ++ks) {
#pragma unroll
    for (int nt = 0; nt < 2; ++nt) {
      const int n = n0 + nt * 16 + lr;
      bf16x8 fr = loadw8(Woh + n * HD + ks * 32 + lg * 8);
      *reinterpret_cast<bf16x8*>(bo + (ks * 2 + nt) * 512 + l * 8) = fr;
    }
  }

  // ---- biases, Wout, c-state (channel = n0 + nt*16 + lr in both layouts) ----
  float bias[4][2], woutv[2], cst[2];
#pragma unroll
  for (int nt = 0; nt < 2; ++nt) {
    const int n = n0 + nt * 16 + lr;
    bias[0][nt] = bfx[n] + bfh[n];
    bias[1][nt] = bgx[n] + bgh[n];
    bias[2][nt] = box_[n] + boh[n];
    bias[3][nt] = bi[n];
    woutv[nt] = Wout[n];
    cst[nt] = c0[n];
  }
  const float boutv = bout[0];

  // ---- stage h0 (all 16 rows incl. pad) and x_0 into buffer 0 ----
  for (int idx = tid; idx < 16 * 256; idx += 512) {
    A_sh[(idx >> 8) * ASTR + (idx & 255)] = f2bf(h0[idx & 255]);
  }
  {
    const int row = tid >> 5, k = tid & 31;
    if (row < 4) {
      A_sh[row * ASTR + 256 + k] = f2bf(x[((size_t)(wg * 4 + row) * T_LEN) * 32 + k]);
    } else {
      A_sh[row * ASTR + 256 + k] = 0;  // pad rows: finite x
    }
  }
  __syncthreads();

  const float* xp = x + (size_t)(wg * 4 + ((tid >> 5) & 3)) * T_LEN * 32 + (tid & 31);
  float* R_w = R_sh + w * (8 * 16 * 4);
  const int akoff = lg * 8;

  for (int t = 0; t < T_LEN; ++t) {
    const int cur = t & 1;
    const short* Arow = A_sh + cur * ABUF + lr * ASTR;
    short* Anxt = A_sh + (cur ^ 1) * ABUF;

    // finalize previous step's output (shadowed by this step's MFMAs)
    if (t > 0 && w == 0 && l < 4) {
      float s = boutv;
#pragma unroll
      for (int ww = 0; ww < 8; ++ww) s += out_part[cur ^ 1][l][ww];
      out[(size_t)(wg * 4 + l) * T_LEN + (t - 1)] = s;
    }

    // prefetch x_{t+1} (rows 0..3 only)
    float xval = 0.0f;
    if (tid < 128) {
      const int tn = (t + 1 < T_LEN) ? (t + 1) : (T_LEN - 1);
      xval = xp[(size_t)tn * 32];
    }

    // acc init with biases (splat over rows)
    f32x4 acc[4][2];
#pragma unroll
    for (int g = 0; g < 4; ++g) {
#pragma unroll
      for (int nt = 0; nt < 2; ++nt) {
        f32x4 v; v[0] = bias[g][nt]; v[1] = bias[g][nt]; v[2] = bias[g][nt]; v[3] = bias[g][nt];
        acc[g][nt] = v;
      }
    }

    // x K-step (register B, lane-group masked zeros)
    {
      const bf16x8 ax = *reinterpret_cast<const bf16x8*>(Arow + 256 + akoff);
#pragma unroll
      for (int g = 0; g < 4; ++g) {
#pragma unroll
        for (int nt = 0; nt < 2; ++nt) {
          acc[g][nt] = __builtin_amdgcn_mfma_f32_16x16x32_bf16(ax, Bx[g][nt], acc[g][nt], 0, 0, 0);
        }
      }
    }
    // recurrent K-steps 0..6: f,g from regs; o from LDS
#pragma unroll
    for (int ks = 0; ks < 7; ++ks) {
      const bf16x8 a = *reinterpret_cast<const bf16x8*>(Arow + ks * 32 + akoff);
#pragma unroll
      for (int nt = 0; nt < 2; ++nt) {
        acc[0][nt] = __builtin_amdgcn_mfma_f32_16x16x32_bf16(a, Bf[ks][nt], acc[0][nt], 0, 0, 0);
        acc[1][nt] = __builtin_amdgcn_mfma_f32_16x16x32_bf16(a, Bg[ks][nt], acc[1][nt], 0, 0, 0);
        const bf16x8 b = *reinterpret_cast<const bf16x8*>(bo + (ks * 2 + nt) * 512 + l * 8);
        acc[2][nt] = __builtin_amdgcn_mfma_f32_16x16x32_bf16(a, b, acc[2][nt], 0, 0, 0);
      }
    }
    // K-step 7: all register-resident
    {
      const bf16x8 a = *reinterpret_cast<const bf16x8*>(Arow + 7 * 32 + akoff);
#pragma unroll
      for (int nt = 0; nt < 2; ++nt) {
        acc[0][nt] = __builtin_amdgcn_mfma_f32_16x16x32_bf16(a, Bf[7][nt], acc[0][nt], 0, 0, 0);
        acc[1][nt] = __builtin_amdgcn_mfma_f32_16x16x32_bf16(a, Bg[7][nt], acc[1][nt], 0, 0, 0);
        acc[2][nt] = __builtin_amdgcn_mfma_f32_16x16x32_bf16(a, Bo7[nt], acc[2][nt], 0, 0, 0);
      }
    }

    // ---- intra-wave redistribution: MFMA D layout -> (row=lg, ch=n0+nt*16+lr) ----
    // Valid rows 0..3 live in lg==0 lanes' acc[..][0..3]. Write [gnt][lam][rho].
    if (lg == 0) {
#pragma unroll
      for (int g = 0; g < 4; ++g) {
#pragma unroll
        for (int nt = 0; nt < 2; ++nt) {
          *reinterpret_cast<f32x4*>(R_w + (g * 2 + nt) * 64 + lr * 4) = acc[g][nt];
        }
      }
    }
    float pre[4][2];
#pragma unroll
    for (int g = 0; g < 4; ++g) {
#pragma unroll
      for (int nt = 0; nt < 2; ++nt) {
        pre[g][nt] = R_w[(g * 2 + nt) * 64 + lr * 4 + lg];
      }
    }

    // ---- activations: 2 gate-sets per lane (row = lg, ch = n0 + nt*16 + lr) ----
    short hpk[2];
    float po = 0.0f;
#pragma unroll
    for (int nt = 0; nt < 2; ++nt) {
      const float fv = sigm(pre[0][nt]);
      const float gv = tanh_(pre[1][nt]);
      const float ov = sigm(pre[2][nt]);
      const float iv = sigm(pre[3][nt]);
      float c = fv * cst[nt] + iv * gv;
      cst[nt] = c;
      const float hv = ov * tanh_(c);
      hpk[nt] = f2bf(hv);
      po += ov * woutv[nt];
    }
    // reduce po over the 16 channels (lr) within the row group
#pragma unroll
    for (int mk = 1; mk < 16; mk <<= 1) {
      po += __shfl_xor(po, mk, 64);
    }

    // writes into the ALTERNATE buffer
    Anxt[lg * ASTR + n0 + lr]      = hpk[0];
    Anxt[lg * ASTR + n0 + 16 + lr] = hpk[1];
    if (tid < 128) Anxt[(tid >> 5) * ASTR + 256 + (tid & 31)] = f2bf(xval);
    if (lr == 0) out_part[cur][lg][w] = po;

    __syncthreads();  // single per-step barrier
  }

  // final output
  if (w == 0 && l < 4) {
    float s = boutv;
#pragma unroll
    for (int ww = 0; ww < 8; ++ww) s += out_part[(T_LEN - 1) & 1][l][ww];
    out[(size_t)(wg * 4 + l) * T_LEN + (T_LEN - 1)] = s;
  }
}

extern "C" void kernel_launch(void* const* d_in, const int* in_sizes, int n_in,
                              void* d_out, int out_size, void* d_ws, size_t ws_size,
                              hipStream_t stream) {
  const float* x    = (const float*)d_in[0];
  const float* c0   = (const float*)d_in[1];
  const float* h0   = (const float*)d_in[2];
  const float* Wi   = (const float*)d_in[3];
  const float* bi   = (const float*)d_in[4];
  const float* Wfx  = (const float*)d_in[5];
  const float* bfx  = (const float*)d_in[6];
  const float* Wfh  = (const float*)d_in[7];
  const float* bfh  = (const float*)d_in[8];
  const float* Wgx  = (const float*)d_in[9];
  const float* bgx  = (const float*)d_in[10];
  const float* Wgh  = (const float*)d_in[11];
  const float* bgh  = (const float*)d_in[12];
  const float* Wox  = (const float*)d_in[13];
  const float* box_ = (const float*)d_in[14];
  const float* Woh  = (const float*)d_in[15];
  const float* boh  = (const float*)d_in[16];
  const float* Wout = (const float*)d_in[17];
  const float* bout = (const float*)d_in[18];

  ealstm_kernel<<<dim3(32), dim3(512), 0, stream>>>(
      x, c0, h0, Wi, bi, Wfx, bfx, Wfh, bfh,
      Wgx, bgx, Wgh, bgh, Wox, box_, Woh, boh, Wout, bout,
      (float*)d_out);
}

// Round 4
// 5292.863 us; speedup vs baseline: 1.1187x; 1.1187x over previous
//
#include <hip/hip_runtime.h>
#include <hip/hip_bf16.h>

// EA-LSTM persistent kernel for MI355X (gfx950), round 4.
// B=128, T=2048, DYN=8, STAT=24, H=256, OUT=1.
// 8 WGs x 512 threads; WG owns 16 batch rows; wave w owns channels [w*32,w*32+32).
// Register weights: f,g gates (all 8 K-steps) + x-projections (160 VGPR).
// LDS weights: o gate (all 8 K-steps, 128 KB).
// Step structure engineered for MFMA/VALU overlap:
//   FG K-loop (reg MFMAs) -> i/x MFMA burst -> O K-loop (LDS MFMAs) with the
//   c-path activation slices interleaved between the o-MFMAs -> short tail.
// Double-buffered A tile (h,x), ONE barrier per step. Budget ~248 regs: no spill.

#define T_LEN 2048
#define HD 256

typedef __attribute__((ext_vector_type(8))) short bf16x8;
typedef __attribute__((ext_vector_type(4))) float f32x4;

#define LOG2E 1.4426950408889634f

__device__ __forceinline__ short f2bf(float f) {
  unsigned u = __float_as_uint(f);
  unsigned r = (u + 0x7fffu + ((u >> 16) & 1u)) >> 16;
  return (short)r;
}

__device__ __forceinline__ bf16x8 loadw8(const float* p) {
  bf16x8 r;
#pragma unroll
  for (int i = 0; i < 8; ++i) r[i] = f2bf(p[i]);
  return r;
}

__device__ __forceinline__ float sigm(float x) {
  float e = __builtin_amdgcn_exp2f(-LOG2E * x);
  return __builtin_amdgcn_rcpf(1.0f + e);
}

// clamp-free tanh: 1 - 2/(e^{2x}+1); saturates to +/-1 at +/-inf, NaN-free.
__device__ __forceinline__ float tanh_(float x) {
  float e = __builtin_amdgcn_exp2f((2.0f * LOG2E) * x);
  return 1.0f - 2.0f * __builtin_amdgcn_rcpf(e + 1.0f);
}

// A tile: 16 rows x 296 cols bf16 (0..255 = h, 256..287 = x_t, 288+ pad).
#define ASTR 296
#define ABUF (16 * ASTR)

__global__ __launch_bounds__(512, 2) void ealstm_kernel(
    const float* __restrict__ x, const float* __restrict__ c0, const float* __restrict__ h0,
    const float* __restrict__ Wi, const float* __restrict__ bi,
    const float* __restrict__ Wfx, const float* __restrict__ bfx,
    const float* __restrict__ Wfh, const float* __restrict__ bfh,
    const float* __restrict__ Wgx, const float* __restrict__ bgx,
    const float* __restrict__ Wgh, const float* __restrict__ bgh,
    const float* __restrict__ Wox, const float* __restrict__ box_,
    const float* __restrict__ Woh, const float* __restrict__ boh,
    const float* __restrict__ Wout, const float* __restrict__ bout,
    float* __restrict__ out)
{
  __shared__ __attribute__((aligned(16))) short A_sh[2 * ABUF];        // 18944 B
  __shared__ __attribute__((aligned(16))) short Bo_sh[8 * 16 * 512];   // 131072 B
  __shared__ float out_part[2][8][16];                                 // 1024 B

  const int tid = threadIdx.x;
  const int w   = tid >> 6;
  const int l   = tid & 63;
  const int lr  = l & 15;
  const int lg  = l >> 4;
  const int n0  = w * 32;
  const int wg  = blockIdx.x;

  // ---- register-resident weights: f,g recurrent + all x-projections ----
  bf16x8 Bf[8][2], Bg[8][2], Bx[4][2];
#pragma unroll
  for (int ks = 0; ks < 8; ++ks) {
#pragma unroll
    for (int nt = 0; nt < 2; ++nt) {
      const int n = n0 + nt * 16 + lr;
      const int k = ks * 32 + lg * 8;
      Bf[ks][nt] = loadw8(Wfh + n * HD + k);
      Bg[ks][nt] = loadw8(Wgh + n * HD + k);
    }
  }
  {
    bf16x8 z = (bf16x8)(short)0;
    const float* WxArr[3] = {Wfx, Wgx, Wox};
#pragma unroll
    for (int nt = 0; nt < 2; ++nt) {
      const int n = n0 + nt * 16 + lr;
#pragma unroll
      for (int g = 0; g < 3; ++g) {
        Bx[g][nt] = (lg == 0) ? loadw8(WxArr[g] + n * 8) : z;
      }
      Bx[3][nt] = (lg >= 1) ? loadw8(Wi + n * 24 + (lg - 1) * 8) : z;
    }
  }

  // ---- LDS-resident: o-gate, all 8 K-steps ----
  short* bo = Bo_sh + w * (16 * 512);
#pragma unroll
  for (int ks = 0; ks < 8; ++ks) {
#pragma unroll
    for (int nt = 0; nt < 2; ++nt) {
      const int n = n0 + nt * 16 + lr;
      bf16x8 fr = loadw8(Woh + n * HD + ks * 32 + lg * 8);
      *reinterpret_cast<bf16x8*>(bo + (ks * 2 + nt) * 512 + l * 8) = fr;
    }
  }

  // ---- biases, Wout, c-state ----
  float bias[4][2], woutv[2];
  f32x4 cst[2];
#pragma unroll
  for (int nt = 0; nt < 2; ++nt) {
    const int n = n0 + nt * 16 + lr;
    bias[0][nt] = bfx[n] + bfh[n];
    bias[1][nt] = bgx[n] + bgh[n];
    bias[2][nt] = box_[n] + boh[n];
    bias[3][nt] = bi[n];
    woutv[nt] = Wout[n];
    const float c0v = c0[n];
    f32x4 cv; cv[0] = c0v; cv[1] = c0v; cv[2] = c0v; cv[3] = c0v;
    cst[nt] = cv;
  }
  const float boutv = bout[0];

  // ---- stage h0 and x_0 into buffer 0 ----
  for (int idx = tid; idx < 16 * 256; idx += 512) {
    A_sh[(idx >> 8) * ASTR + (idx & 255)] = f2bf(h0[idx & 255]);
  }
  {
    const int row = tid >> 5, k = tid & 31;
    A_sh[row * ASTR + 256 + k] = f2bf(x[((size_t)(wg * 16 + row) * T_LEN) * 32 + k]);
  }
  __syncthreads();

  const float* xp = x + (size_t)(wg * 16 + (tid >> 5)) * T_LEN * 32 + (tid & 31);
  float* outp = out + (size_t)(wg * 16 + lr) * T_LEN;
  const int akoff = lg * 8;

  for (int t = 0; t < T_LEN; ++t) {
    const int cur = t & 1;
    const short* ArowC = A_sh + cur * ABUF + lr * ASTR;
    short* Anxt = A_sh + (cur ^ 1) * ABUF;

    // finalize previous step's output (hidden under this step's MFMA phase)
    if (t > 0 && w == 0 && l < 16) {
      float s = boutv;
#pragma unroll
      for (int ww = 0; ww < 8; ++ww) s += out_part[cur ^ 1][ww][l];
      outp[t - 1] = s;
    }

    // prefetch x_{t+1}
    const int tn = (t + 1 < T_LEN) ? (t + 1) : (T_LEN - 1);
    const float xval = xp[(size_t)tn * 32];

    // acc init with biases
    f32x4 acc[4][2];
#pragma unroll
    for (int g = 0; g < 4; ++g) {
#pragma unroll
      for (int nt = 0; nt < 2; ++nt) {
        f32x4 v; v[0] = bias[g][nt]; v[1] = bias[g][nt]; v[2] = bias[g][nt]; v[3] = bias[g][nt];
        acc[g][nt] = v;
      }
    }

    // ---- FG K-loop: register-weight MFMAs ----
#pragma unroll
    for (int ks = 0; ks < 8; ++ks) {
      const bf16x8 a = *reinterpret_cast<const bf16x8*>(ArowC + ks * 32 + akoff);
      acc[0][0] = __builtin_amdgcn_mfma_f32_16x16x32_bf16(a, Bf[ks][0], acc[0][0], 0, 0, 0);
      acc[0][1] = __builtin_amdgcn_mfma_f32_16x16x32_bf16(a, Bf[ks][1], acc[0][1], 0, 0, 0);
      acc[1][0] = __builtin_amdgcn_mfma_f32_16x16x32_bf16(a, Bg[ks][0], acc[1][0], 0, 0, 0);
      acc[1][1] = __builtin_amdgcn_mfma_f32_16x16x32_bf16(a, Bg[ks][1], acc[1][1], 0, 0, 0);
    }

    // ---- i/x MFMA burst (i first: slices consume acc[3] soonest) ----
    {
      const bf16x8 axv = *reinterpret_cast<const bf16x8*>(ArowC + 256 + akoff);
      acc[3][0] = __builtin_amdgcn_mfma_f32_16x16x32_bf16(axv, Bx[3][0], acc[3][0], 0, 0, 0);
      acc[3][1] = __builtin_amdgcn_mfma_f32_16x16x32_bf16(axv, Bx[3][1], acc[3][1], 0, 0, 0);
      acc[0][0] = __builtin_amdgcn_mfma_f32_16x16x32_bf16(axv, Bx[0][0], acc[0][0], 0, 0, 0);
      acc[0][1] = __builtin_amdgcn_mfma_f32_16x16x32_bf16(axv, Bx[0][1], acc[0][1], 0, 0, 0);
      acc[1][0] = __builtin_amdgcn_mfma_f32_16x16x32_bf16(axv, Bx[1][0], acc[1][0], 0, 0, 0);
      acc[1][1] = __builtin_amdgcn_mfma_f32_16x16x32_bf16(axv, Bx[1][1], acc[1][1], 0, 0, 0);
      acc[2][0] = __builtin_amdgcn_mfma_f32_16x16x32_bf16(axv, Bx[2][0], acc[2][0], 0, 0, 0);
      acc[2][1] = __builtin_amdgcn_mfma_f32_16x16x32_bf16(axv, Bx[2][1], acc[2][1], 0, 0, 0);
    }

    // ---- O K-loop: LDS-weight MFMAs with c-path activation slices woven in ----
    f32x4 tcv[2];
#pragma unroll
    for (int ks = 0; ks < 8; ++ks) {
      const bf16x8 a  = *reinterpret_cast<const bf16x8*>(ArowC + ks * 32 + akoff);
      const bf16x8 b0 = *reinterpret_cast<const bf16x8*>(bo + (ks * 2 + 0) * 512 + l * 8);
      const bf16x8 b1 = *reinterpret_cast<const bf16x8*>(bo + (ks * 2 + 1) * 512 + l * 8);
      acc[2][0] = __builtin_amdgcn_mfma_f32_16x16x32_bf16(a, b0, acc[2][0], 0, 0, 0);
      acc[2][1] = __builtin_amdgcn_mfma_f32_16x16x32_bf16(a, b1, acc[2][1], 0, 0, 0);
      // slice ks: (nt = ks>>2, r = ks&3) — f,g,i -> c -> tanh(c); VALU overlaps MFMA
      {
        const int nt = ks >> 2, r = ks & 3;
        const float sf = sigm(acc[0][nt][r]);
        const float tg = tanh_(acc[1][nt][r]);
        const float si = sigm(acc[3][nt][r]);
        const float c  = sf * cst[nt][r] + si * tg;
        cst[nt][r] = c;
        tcv[nt][r] = tanh_(c);
      }
    }

    // ---- tail: o-activation, h, pack, writes, output partials ----
    short hpk[2][4];
    f32x4 po; po[0] = 0.f; po[1] = 0.f; po[2] = 0.f; po[3] = 0.f;
#pragma unroll
    for (int nt = 0; nt < 2; ++nt) {
#pragma unroll
      for (int r = 0; r < 4; ++r) {
        const float so = sigm(acc[2][nt][r]);
        const float hv = so * tcv[nt][r];
        hpk[nt][r] = f2bf(hv);
        po[r] += so * woutv[nt];
      }
    }
#pragma unroll
    for (int r = 0; r < 4; ++r) {
#pragma unroll
      for (int mk = 1; mk < 16; mk <<= 1) {
        po[r] += __shfl_xor(po[r], mk, 64);
      }
    }

    // writes into the ALTERNATE buffer (no barrier needed before)
#pragma unroll
    for (int nt = 0; nt < 2; ++nt) {
#pragma unroll
      for (int r = 0; r < 4; ++r) {
        Anxt[(lg * 4 + r) * ASTR + (n0 + nt * 16 + lr)] = hpk[nt][r];
      }
    }
    Anxt[(tid >> 5) * ASTR + 256 + (tid & 31)] = f2bf(xval);
    if (lr == 0) {
#pragma unroll
      for (int r = 0; r < 4; ++r) out_part[cur][w][lg * 4 + r] = po[r];
    }

    __syncthreads();  // single per-step barrier
  }

  // final output
  if (w == 0 && l < 16) {
    float s = boutv;
#pragma unroll
    for (int ww = 0; ww < 8; ++ww) s += out_part[(T_LEN - 1) & 1][ww][l];
    outp[T_LEN - 1] = s;
  }
}

extern "C" void kernel_launch(void* const* d_in, const int* in_sizes, int n_in,
                              void* d_out, int out_size, void* d_ws, size_t ws_size,
                              hipStream_t stream) {
  const float* x    = (const float*)d_in[0];
  const float* c0   = (const float*)d_in[1];
  const float* h0   = (const float*)d_in[2];
  const float* Wi   = (const float*)d_in[3];
  const float* bi   = (const float*)d_in[4];
  const float* Wfx  = (const float*)d_in[5];
  const float* bfx  = (const float*)d_in[6];
  const float* Wfh  = (const float*)d_in[7];
  const float* bfh  = (const float*)d_in[8];
  const float* Wgx  = (const float*)d_in[9];
  const float* bgx  = (const float*)d_in[10];
  const float* Wgh  = (const float*)d_in[11];
  const float* bgh  = (const float*)d_in[12];
  const float* Wox  = (const float*)d_in[13];
  const float* box_ = (const float*)d_in[14];
  const float* Woh  = (const float*)d_in[15];
  const float* boh  = (const float*)d_in[16];
  const float* Wout = (const float*)d_in[17];
  const float* bout = (const float*)d_in[18];

  ealstm_kernel<<<dim3(8), dim3(512), 0, stream>>>(
      x, c0, h0, Wi, bi, Wfx, bfx, Wfh, bfh,
      Wgx, bgx, Wgh, bgh, Wox, box_, Woh, boh, Wout, bout,
      (float*)d_out);
}